// Round 1
// baseline (144.122 us; speedup 1.0000x reference)
//
#include <hip/hip_runtime.h>

typedef float f32x4 __attribute__((ext_vector_type(4)));
typedef short s16x4 __attribute__((ext_vector_type(4)));

#define LOG2E 1.4426950408889634f

// ---- bf16 helpers (bit-level, RNE) ----
__device__ __forceinline__ short f2bf(float f) {
  unsigned u = __float_as_uint(f);
  unsigned r = (u + 0x7fffu + ((u >> 16) & 1u)) >> 16;
  return (short)r;
}
__device__ __forceinline__ float bf2f(short s) {
  return __uint_as_float(((unsigned)(unsigned short)s) << 16);
}

// mfma_f32_16x16x16_bf16 (gfx90a-era builtin, supported on gfx950)
// A: row=lane&15, k=4*(lane>>4)+e ; B: col=lane&15, k=4*(lane>>4)+e
// D: col=lane&15, row=4*(lane>>4)+reg   [HW-verified shape-determined C/D layout]
__device__ __forceinline__ f32x4 mfma16(s16x4 a, s16x4 b, f32x4 c) {
  return __builtin_amdgcn_mfma_f32_16x16x16bf16_1k(a, b, c, 0, 0, 0);
}

// ============================================================
// Kernel 0: split W^T into bf16 hi/lo.  wt[n][c], n: 0-63 q, 64-127 k, 128-191 v
// ============================================================
__global__ __launch_bounds__(256) void prep_w(
    const float* __restrict__ Wq, const float* __restrict__ Wk, const float* __restrict__ Wv,
    short* __restrict__ wt_hi, short* __restrict__ wt_lo) {
  int idx = blockIdx.x * 256 + threadIdx.x;   // 192*1024 total
  int n = idx >> 10;
  int c = idx & 1023;
  const float* W = (n < 64) ? Wq : ((n < 128) ? Wk : Wv);
  float v = W[c * 64 + (n & 63)];
  short hi = f2bf(v);
  short lo = f2bf(v - bf2f(hi));
  wt_hi[idx] = hi;
  wt_lo[idx] = lo;
}

// ============================================================
// Kernel 1: QKV projection. grid 256 x 512 threads (8 waves).
// wave = (mfrag: 16 tokens, ngrp: 3 N-fragments {2 split-type + 1 v-type})
// q,k: split-bf16 product (xh*Wh + xl*Wh + xh*Wl) -> fp32 -> re-split hi/lo.
// v: plain bf16 product, stored TRANSPOSED v_t[b][h][t].
// ============================================================
__global__ __launch_bounds__(512) void proj_qkv(
    const float* __restrict__ x,
    const short* __restrict__ wt_hi, const short* __restrict__ wt_lo,
    const float* __restrict__ bq, const float* __restrict__ bk, const float* __restrict__ bv,
    short* __restrict__ q_hi, short* __restrict__ q_lo,
    short* __restrict__ k_hi, short* __restrict__ k_lo,
    short* __restrict__ v_t) {
  const int lane = threadIdx.x & 63;
  const int wv = threadIdx.x >> 6;
  const int col = lane & 15;
  const int g = lane >> 4;
  const int mfrag = wv >> 2;
  const int ngrp = wv & 3;
  const int tokbase = blockIdx.x * 32 + mfrag * 16;

  const int nfA = ngrp * 2;      // 0,2 -> q ; 4,6 -> k
  const int nfB = nfA + 1;       // 1,3 -> q ; 5,7 -> k
  const int nfV = 8 + ngrp;      // v fragments

  const float* xp  = x + (size_t)(tokbase + col) * 1024 + g * 4;
  const short* pAh = wt_hi + (size_t)(nfA * 16 + col) * 1024 + g * 4;
  const short* pAl = wt_lo + (size_t)(nfA * 16 + col) * 1024 + g * 4;
  const short* pBh = wt_hi + (size_t)(nfB * 16 + col) * 1024 + g * 4;
  const short* pBl = wt_lo + (size_t)(nfB * 16 + col) * 1024 + g * 4;
  const short* pVh = wt_hi + (size_t)(nfV * 16 + col) * 1024 + g * 4;

  f32x4 accA = {0.f, 0.f, 0.f, 0.f};
  f32x4 accB = {0.f, 0.f, 0.f, 0.f};
  f32x4 accV = {0.f, 0.f, 0.f, 0.f};

  for (int c = 0; c < 1024; c += 16) {
    f32x4 xa = *(const f32x4*)(xp + c);
    s16x4 xh, xl;
#pragma unroll
    for (int i = 0; i < 4; ++i) {
      float f = xa[i];
      short h = f2bf(f);
      xh[i] = h;
      xl[i] = f2bf(f - bf2f(h));
    }
    s16x4 ah = *(const s16x4*)(pAh + c);
    s16x4 al = *(const s16x4*)(pAl + c);
    s16x4 bh = *(const s16x4*)(pBh + c);
    s16x4 bl = *(const s16x4*)(pBl + c);
    s16x4 vh = *(const s16x4*)(pVh + c);
    accA = mfma16(xh, ah, accA);
    accB = mfma16(xh, bh, accB);
    accV = mfma16(xh, vh, accV);
    accA = mfma16(xl, ah, accA);
    accB = mfma16(xl, bh, accB);
    accA = mfma16(xh, al, accA);
    accB = mfma16(xh, bl, accB);
  }

  // epilogue: bias, split, store
  {
    const int hA = (nfA & 3) * 16 + col;
    const float bias = (nfA < 4) ? bq[hA] : bk[hA];
    short* dh = (nfA < 4) ? q_hi : k_hi;
    short* dl = (nfA < 4) ? q_lo : k_lo;
#pragma unroll
    for (int r = 0; r < 4; ++r) {
      const int tok = tokbase + 4 * g + r;
      float f = accA[r] + bias;
      short hi = f2bf(f);
      short lo = f2bf(f - bf2f(hi));
      dh[(size_t)tok * 64 + hA] = hi;
      dl[(size_t)tok * 64 + hA] = lo;
    }
  }
  {
    const int hB = (nfB & 3) * 16 + col;
    const float bias = (nfB < 4) ? bq[hB] : bk[hB];
    short* dh = (nfB < 4) ? q_hi : k_hi;
    short* dl = (nfB < 4) ? q_lo : k_lo;
#pragma unroll
    for (int r = 0; r < 4; ++r) {
      const int tok = tokbase + 4 * g + r;
      float f = accB[r] + bias;
      short hi = f2bf(f);
      short lo = f2bf(f - bf2f(hi));
      dh[(size_t)tok * 64 + hB] = hi;
      dl[(size_t)tok * 64 + hB] = lo;
    }
  }
  {
    const int hV = (nfV - 8) * 16 + col;
    const float bias = bv[hV];
#pragma unroll
    for (int r = 0; r < 4; ++r) {
      const int tok = tokbase + 4 * g + r;
      const int bb = tok >> 11;
      const int tl = tok & 2047;
      v_t[((size_t)bb * 64 + hV) * 2048 + tl] = f2bf(accV[r] + bias);
    }
  }
}

// ============================================================
// Kernel 2: causal flash attention. grid = 4 batches x 64 pairs, 256 thr (4 waves).
// Block handles q-tiles t and 127-t (16 queries each) -> uniform work.
// Waves split key-tiles mod 4 with private online softmax; merge in LDS.
// S^T = mfma(K_frag, Q_frag): D has col=q (lane&15), row=key (4g+reg).
// That D layout IS the A-frag layout for PV: O^T = mfma(V^T_frag, P_frag).
// m,l live per-lane (q = lane&15) -> in-lane rescale, no shuffles in PV path.
// ============================================================
__global__ __launch_bounds__(256) void attn(
    const short* __restrict__ q_hi, const short* __restrict__ q_lo,
    const short* __restrict__ k_hi, const short* __restrict__ k_lo,
    const short* __restrict__ v_t, float* __restrict__ out) {
  const int lane = threadIdx.x & 63;
  const int wv = threadIdx.x >> 6;
  const int col = lane & 15;
  const int g = lane >> 4;
  const int pr = blockIdx.x & 63;
  const int b = blockIdx.x >> 6;

  __shared__ float lds_O[4 * 64 * 18];
  __shared__ float lds_m[64];
  __shared__ float lds_l[64];

  const short* kh_b = k_hi + (size_t)b * 2048 * 64;
  const short* kl_b = k_lo + (size_t)b * 2048 * 64;
  const short* vt_b = v_t + (size_t)b * 64 * 2048;

#pragma unroll 1
  for (int half = 0; half < 2; ++half) {
    const int t = half ? (127 - pr) : pr;
    const int qb = t * 16;

    const short* qrh = q_hi + (size_t)(b * 2048 + qb + col) * 64 + g * 4;
    const short* qrl = q_lo + (size_t)(b * 2048 + qb + col) * 64 + g * 4;
    s16x4 qh[4], ql[4];
#pragma unroll
    for (int s = 0; s < 4; ++s) {
      qh[s] = *(const s16x4*)(qrh + 16 * s);
      ql[s] = *(const s16x4*)(qrl + 16 * s);
    }

    f32x4 o0 = {0,0,0,0}, o1 = {0,0,0,0}, o2 = {0,0,0,0}, o3 = {0,0,0,0};
    float m = -3.0e38f, l = 0.0f;

    for (int kt = wv; kt <= t; kt += 4) {
      const int kb = kt * 16;
      const short* krh = kh_b + (size_t)(kb + col) * 64 + g * 4;
      const short* krl = kl_b + (size_t)(kb + col) * 64 + g * 4;
      s16x4 kh[4], kl4[4];
#pragma unroll
      for (int s = 0; s < 4; ++s) {
        kh[s]  = *(const s16x4*)(krh + 16 * s);
        kl4[s] = *(const s16x4*)(krl + 16 * s);
      }
      const short* vrow = vt_b + (size_t)col * 2048 + kb + 4 * g;
      s16x4 vf0 = *(const s16x4*)(vrow);
      s16x4 vf1 = *(const s16x4*)(vrow + 16 * 2048);
      s16x4 vf2 = *(const s16x4*)(vrow + 32 * 2048);
      s16x4 vf3 = *(const s16x4*)(vrow + 48 * 2048);

      // S^T = (Kh+Kl)(Qh+Ql) ~= KhQh + KhQl + KlQh   (split-bf16, 3 indep chains)
      f32x4 sA = {0,0,0,0}, sB = {0,0,0,0}, sC = {0,0,0,0};
#pragma unroll
      for (int s = 0; s < 4; ++s) {
        sA = mfma16(kh[s],  qh[s], sA);
        sB = mfma16(kh[s],  ql[s], sB);
        sC = mfma16(kl4[s], qh[s], sC);
      }
      float s0 = sA[0] + sB[0] + sC[0];
      float s1 = sA[1] + sB[1] + sC[1];
      float s2 = sA[2] + sB[2] + sC[2];
      float s3 = sA[3] + sB[3] + sC[3];
      if (kt == t) {              // diagonal tile: key_local > q_local masked
        const int keyl = 4 * g;
        if (keyl + 0 > col) s0 = -3.0e38f;
        if (keyl + 1 > col) s1 = -3.0e38f;
        if (keyl + 2 > col) s2 = -3.0e38f;
        if (keyl + 3 > col) s3 = -3.0e38f;
      }
      float mx = fmaxf(fmaxf(s0, s1), fmaxf(s2, s3));
      mx = fmaxf(mx, __shfl_xor(mx, 16));
      mx = fmaxf(mx, __shfl_xor(mx, 32));
      const float mnew = fmaxf(m, mx);
      const float sc2 = __builtin_amdgcn_exp2f((m - mnew) * LOG2E);
      const float p0 = __builtin_amdgcn_exp2f((s0 - mnew) * LOG2E);
      const float p1 = __builtin_amdgcn_exp2f((s1 - mnew) * LOG2E);
      const float p2 = __builtin_amdgcn_exp2f((s2 - mnew) * LOG2E);
      const float p3 = __builtin_amdgcn_exp2f((s3 - mnew) * LOG2E);
      l = l * sc2 + (p0 + p1 + p2 + p3);   // group-partial l (reduced at end)
      o0 *= sc2; o1 *= sc2; o2 *= sc2; o3 *= sc2;
      s16x4 pb;
      pb[0] = f2bf(p0); pb[1] = f2bf(p1); pb[2] = f2bf(p2); pb[3] = f2bf(p3);
      o0 = mfma16(vf0, pb, o0);   // O^T[h][q], h = 4g+reg + 16*frag
      o1 = mfma16(vf1, pb, o1);
      o2 = mfma16(vf2, pb, o2);
      o3 = mfma16(vf3, pb, o3);
      m = mnew;
    }

    // merge the 4 waves' partial (m, l, O^T) through LDS
    l += __shfl_xor(l, 16);
    l += __shfl_xor(l, 32);
    if (g == 0) {
      lds_m[wv * 16 + col] = m;
      lds_l[wv * 16 + col] = l;
    }
#pragma unroll
    for (int r = 0; r < 4; ++r) {
      lds_O[(wv * 64 +  0 + 4 * g + r) * 18 + col] = o0[r];
      lds_O[(wv * 64 + 16 + 4 * g + r) * 18 + col] = o1[r];
      lds_O[(wv * 64 + 32 + 4 * g + r) * 18 + col] = o2[r];
      lds_O[(wv * 64 + 48 + 4 * g + r) * 18 + col] = o3[r];
    }
    __syncthreads();
    {
      const int q = threadIdx.x & 15;
      const int hq = threadIdx.x >> 4;   // 0..15
      const float m0 = lds_m[q], m1 = lds_m[16 + q], m2 = lds_m[32 + q], m3 = lds_m[48 + q];
      float M = fmaxf(fmaxf(m0, m1), fmaxf(m2, m3));
      const float e0 = __builtin_amdgcn_exp2f((m0 - M) * LOG2E);
      const float e1 = __builtin_amdgcn_exp2f((m1 - M) * LOG2E);
      const float e2 = __builtin_amdgcn_exp2f((m2 - M) * LOG2E);
      const float e3 = __builtin_amdgcn_exp2f((m3 - M) * LOG2E);
      const float L = e0 * lds_l[q] + e1 * lds_l[16 + q] + e2 * lds_l[32 + q] + e3 * lds_l[48 + q];
      const float invL = 1.0f / L;
#pragma unroll
      for (int e = 0; e < 4; ++e) {
        const int h = hq * 4 + e;
        float acc = e0 * lds_O[(0 * 64 + h) * 18 + q]
                  + e1 * lds_O[(1 * 64 + h) * 18 + q]
                  + e2 * lds_O[(2 * 64 + h) * 18 + q]
                  + e3 * lds_O[(3 * 64 + h) * 18 + q];
        out[(size_t)(b * 2048 + qb + q) * 64 + h] = acc * invL;
      }
    }
    __syncthreads();
  }
}

// ============================================================
extern "C" void kernel_launch(void* const* d_in, const int* in_sizes, int n_in,
                              void* d_out, int out_size, void* d_ws, size_t ws_size,
                              hipStream_t stream) {
  const float* x  = (const float*)d_in[0];
  const float* Wq = (const float*)d_in[1];
  const float* bq = (const float*)d_in[2];
  const float* Wk = (const float*)d_in[3];
  const float* bk = (const float*)d_in[4];
  const float* Wv = (const float*)d_in[5];
  const float* bv = (const float*)d_in[6];
  float* out = (float*)d_out;

  char* ws = (char*)d_ws;
  short* wt_hi = (short*)(ws);                       // 192*1024*2 = 393216 B
  short* wt_lo = (short*)(ws + 393216);
  short* q_hi  = (short*)(ws + 786432);              // 8192*64*2 = 1 MiB each
  short* q_lo  = (short*)(ws + 786432 + 1048576);
  short* k_hi  = (short*)(ws + 786432 + 2 * 1048576);
  short* k_lo  = (short*)(ws + 786432 + 3 * 1048576);
  short* v_t   = (short*)(ws + 786432 + 4 * 1048576);  // end: 6,029,312 B

  hipLaunchKernelGGL(prep_w, dim3(768), dim3(256), 0, stream, Wq, Wk, Wv, wt_hi, wt_lo);
  hipLaunchKernelGGL(proj_qkv, dim3(256), dim3(512), 0, stream,
                     x, wt_hi, wt_lo, bq, bk, bv, q_hi, q_lo, k_hi, k_lo, v_t);
  hipLaunchKernelGGL(attn, dim3(256), dim3(256), 0, stream,
                     q_hi, q_lo, k_hi, k_lo, v_t, out);
}

// Round 2
// 99.305 us; speedup vs baseline: 1.4513x; 1.4513x over previous
//
#include <hip/hip_runtime.h>

typedef float f32x4 __attribute__((ext_vector_type(4)));
typedef short s16x4 __attribute__((ext_vector_type(4)));
typedef short s16x8 __attribute__((ext_vector_type(8)));

#define LOG2E 1.4426950408889634f

// ---- bf16 helpers (bit-level, RNE) ----
__device__ __forceinline__ short f2bf(float f) {
  unsigned u = __float_as_uint(f);
  unsigned r = (u + 0x7fffu + ((u >> 16) & 1u)) >> 16;
  return (short)r;
}
__device__ __forceinline__ float bf2f(short s) {
  return __uint_as_float(((unsigned)(unsigned short)s) << 16);
}

// 16x16x16 bf16 (K=16). A: row=lane&15, k=4g+e ; D: col=lane&15, row=4g+reg
__device__ __forceinline__ f32x4 mfma16(s16x4 a, s16x4 b, f32x4 c) {
  return __builtin_amdgcn_mfma_f32_16x16x16bf16_1k(a, b, c, 0, 0, 0);
}
// 16x16x32 bf16 (K=32, gfx950). Same C/D layout (shape-determined).
// kappa-matching: A and B both use (g,e) -> elem g*8+e, so any HW k-permutation cancels.
__device__ __forceinline__ f32x4 mfma32(s16x8 a, s16x8 b, f32x4 c) {
  return __builtin_amdgcn_mfma_f32_16x16x32_bf16(a, b, c, 0, 0, 0);
}

// ============================================================
// Kernel 0: split W^T into bf16 hi/lo.  wt[n][c], n: 0-63 q, 64-127 k, 128-191 v
// ============================================================
__global__ __launch_bounds__(256) void prep_w(
    const float* __restrict__ Wq, const float* __restrict__ Wk, const float* __restrict__ Wv,
    short* __restrict__ wt_hi, short* __restrict__ wt_lo) {
  int idx = blockIdx.x * 256 + threadIdx.x;   // 192*1024 total
  int n = idx >> 10;
  int c = idx & 1023;
  const float* W = (n < 64) ? Wq : ((n < 128) ? Wk : Wv);
  float v = W[c * 64 + (n & 63)];
  short hi = f2bf(v);
  short lo = f2bf(v - bf2f(hi));
  wt_hi[idx] = hi;
  wt_lo[idx] = lo;
}

// ============================================================
// Kernel 1: QKV projection. grid 256 x 512 threads (8 waves).
// wave = (mfrag: 16 tokens, ngrp). K-chunk=32 (x32 MFMA), two-stage register
// pipeline: 4 named buffers, loads issued ~2 chunk-computes before use.
// ============================================================
#define P_DECL(S) f32x4 px0##S, px1##S; s16x8 pah##S, pal##S, pbh##S, pbl##S, pvh##S
#define P_LOAD(S, c) do { \
    const int _o = (c) * 32; \
    px0##S = *(const f32x4*)(xp + _o); \
    px1##S = *(const f32x4*)(xp + _o + 4); \
    pah##S = *(const s16x8*)(pAh + _o); \
    pal##S = *(const s16x8*)(pAl + _o); \
    pbh##S = *(const s16x8*)(pBh + _o); \
    pbl##S = *(const s16x8*)(pBl + _o); \
    pvh##S = *(const s16x8*)(pVh + _o); \
  } while (0)
#define P_STEP(S) do { \
    s16x8 _xh, _xl; \
    _Pragma("unroll") \
    for (int _i = 0; _i < 4; ++_i) { \
      float _f = px0##S[_i]; \
      short _h = f2bf(_f); \
      _xh[_i] = _h; _xl[_i] = f2bf(_f - bf2f(_h)); \
      _f = px1##S[_i]; \
      _h = f2bf(_f); \
      _xh[4 + _i] = _h; _xl[4 + _i] = f2bf(_f - bf2f(_h)); \
    } \
    accA = mfma32(_xh, pah##S, accA); \
    accB = mfma32(_xh, pbh##S, accB); \
    accV = mfma32(_xh, pvh##S, accV); \
    accA = mfma32(_xl, pah##S, accA); \
    accB = mfma32(_xl, pbh##S, accB); \
    accA = mfma32(_xh, pal##S, accA); \
    accB = mfma32(_xh, pbl##S, accB); \
  } while (0)

__global__ __launch_bounds__(512, 2) void proj_qkv(
    const float* __restrict__ x,
    const short* __restrict__ wt_hi, const short* __restrict__ wt_lo,
    const float* __restrict__ bq, const float* __restrict__ bk, const float* __restrict__ bv,
    short* __restrict__ q_hi, short* __restrict__ q_lo,
    short* __restrict__ k_hi, short* __restrict__ k_lo,
    short* __restrict__ v_t) {
  const int lane = threadIdx.x & 63;
  const int wv = threadIdx.x >> 6;
  const int col = lane & 15;
  const int g = lane >> 4;
  const int mfrag = wv >> 2;
  const int ngrp = wv & 3;
  const int tokbase = blockIdx.x * 32 + mfrag * 16;

  const int nfA = ngrp * 2;      // 0,2 -> q ; 4,6 -> k
  const int nfB = nfA + 1;       // 1,3 -> q ; 5,7 -> k
  const int nfV = 8 + ngrp;      // v fragments

  const float* xp  = x + (size_t)(tokbase + col) * 1024 + g * 8;
  const short* pAh = wt_hi + (size_t)(nfA * 16 + col) * 1024 + g * 8;
  const short* pAl = wt_lo + (size_t)(nfA * 16 + col) * 1024 + g * 8;
  const short* pBh = wt_hi + (size_t)(nfB * 16 + col) * 1024 + g * 8;
  const short* pBl = wt_lo + (size_t)(nfB * 16 + col) * 1024 + g * 8;
  const short* pVh = wt_hi + (size_t)(nfV * 16 + col) * 1024 + g * 8;

  f32x4 accA = {0.f, 0.f, 0.f, 0.f};
  f32x4 accB = {0.f, 0.f, 0.f, 0.f};
  f32x4 accV = {0.f, 0.f, 0.f, 0.f};

  P_DECL(A); P_DECL(B); P_DECL(C); P_DECL(D);
  P_LOAD(A, 0);
  P_LOAD(B, 1);
#pragma unroll 1
  for (int cc = 0; cc < 8; ++cc) {
    const int c0 = 4 * cc;
    // stage 1: prefetch chunks c0+2, c0+3; consume A (c0), B (c0+1)
    {
      const int c2 = (c0 + 2 < 32) ? c0 + 2 : 31;
      const int c3 = (c0 + 3 < 32) ? c0 + 3 : 31;
      P_LOAD(C, c2);
      P_LOAD(D, c3);
    }
    P_STEP(A);
    P_STEP(B);
    // stage 2: prefetch chunks c0+4, c0+5; consume C (c0+2), D (c0+3)
    {
      const int c4 = (c0 + 4 < 32) ? c0 + 4 : 31;
      const int c5 = (c0 + 5 < 32) ? c0 + 5 : 31;
      P_LOAD(A, c4);
      P_LOAD(B, c5);
    }
    P_STEP(C);
    P_STEP(D);
  }

  // epilogue: bias, split, store
  {
    const int hA = (nfA & 3) * 16 + col;
    const float bias = (nfA < 4) ? bq[hA] : bk[hA];
    short* dh = (nfA < 4) ? q_hi : k_hi;
    short* dl = (nfA < 4) ? q_lo : k_lo;
#pragma unroll
    for (int r = 0; r < 4; ++r) {
      const int tok = tokbase + 4 * g + r;
      float f = accA[r] + bias;
      short hi = f2bf(f);
      short lo = f2bf(f - bf2f(hi));
      dh[(size_t)tok * 64 + hA] = hi;
      dl[(size_t)tok * 64 + hA] = lo;
    }
  }
  {
    const int hB = (nfB & 3) * 16 + col;
    const float bias = (nfB < 4) ? bq[hB] : bk[hB];
    short* dh = (nfB < 4) ? q_hi : k_hi;
    short* dl = (nfB < 4) ? q_lo : k_lo;
#pragma unroll
    for (int r = 0; r < 4; ++r) {
      const int tok = tokbase + 4 * g + r;
      float f = accB[r] + bias;
      short hi = f2bf(f);
      short lo = f2bf(f - bf2f(hi));
      dh[(size_t)tok * 64 + hB] = hi;
      dl[(size_t)tok * 64 + hB] = lo;
    }
  }
  {
    const int hV = (nfV - 8) * 16 + col;
    const float bias = bv[hV];
#pragma unroll
    for (int r = 0; r < 4; ++r) {
      const int tok = tokbase + 4 * g + r;
      const int bb = tok >> 11;
      const int tl = tok & 2047;
      v_t[((size_t)bb * 64 + hV) * 2048 + tl] = f2bf(accV[r] + bias);
    }
  }
}

// ============================================================
// Kernel 2: causal flash attention. grid = 4 batches x 64 pairs, 512 thr (8 waves).
// Block handles q-tiles t and 127-t. Waves split key-tiles mod 8, private
// online softmax, K/V register prefetch (two named buffers), 8-way LDS merge.
// QK^T via x32 MFMA (S^T layout unchanged); PV via x16 (S^T -> A-frag trick).
// ============================================================
#define KV_DECL(S) s16x8 kh0##S, kh1##S, kl0##S, kl1##S; s16x4 vf0##S, vf1##S, vf2##S, vf3##S
#define KV_LOAD(S, ktv) do { \
    const int _kb = (ktv) * 16; \
    const short* _krh = kh_b + (size_t)(_kb + col) * 64 + g * 8; \
    const short* _krl = kl_b + (size_t)(_kb + col) * 64 + g * 8; \
    kh0##S = *(const s16x8*)(_krh); \
    kh1##S = *(const s16x8*)(_krh + 32); \
    kl0##S = *(const s16x8*)(_krl); \
    kl1##S = *(const s16x8*)(_krl + 32); \
    const short* _vrow = vt_b + (size_t)col * 2048 + _kb + 4 * g; \
    vf0##S = *(const s16x4*)(_vrow); \
    vf1##S = *(const s16x4*)(_vrow + 16 * 2048); \
    vf2##S = *(const s16x4*)(_vrow + 32 * 2048); \
    vf3##S = *(const s16x4*)(_vrow + 48 * 2048); \
  } while (0)
#define KV_COMPUTE(S, ktv) do { \
    f32x4 sA = {0,0,0,0}, sB = {0,0,0,0}, sC = {0,0,0,0}; \
    sA = mfma32(kh0##S, qh0, sA); sA = mfma32(kh1##S, qh1, sA); \
    sB = mfma32(kh0##S, ql0, sB); sB = mfma32(kh1##S, ql1, sB); \
    sC = mfma32(kl0##S, qh0, sC); sC = mfma32(kl1##S, qh1, sC); \
    float s0 = sA[0] + sB[0] + sC[0]; \
    float s1 = sA[1] + sB[1] + sC[1]; \
    float s2 = sA[2] + sB[2] + sC[2]; \
    float s3 = sA[3] + sB[3] + sC[3]; \
    if ((ktv) == t) { \
      const int keyl = 4 * g; \
      if (keyl + 0 > col) s0 = -3.0e38f; \
      if (keyl + 1 > col) s1 = -3.0e38f; \
      if (keyl + 2 > col) s2 = -3.0e38f; \
      if (keyl + 3 > col) s3 = -3.0e38f; \
    } \
    float mx = fmaxf(fmaxf(s0, s1), fmaxf(s2, s3)); \
    mx = fmaxf(mx, __shfl_xor(mx, 16)); \
    mx = fmaxf(mx, __shfl_xor(mx, 32)); \
    const float mnew = fmaxf(m, mx); \
    const float sc2 = __builtin_amdgcn_exp2f((m - mnew) * LOG2E); \
    const float p0 = __builtin_amdgcn_exp2f((s0 - mnew) * LOG2E); \
    const float p1 = __builtin_amdgcn_exp2f((s1 - mnew) * LOG2E); \
    const float p2 = __builtin_amdgcn_exp2f((s2 - mnew) * LOG2E); \
    const float p3 = __builtin_amdgcn_exp2f((s3 - mnew) * LOG2E); \
    l = l * sc2 + (p0 + p1 + p2 + p3); \
    o0 *= sc2; o1 *= sc2; o2 *= sc2; o3 *= sc2; \
    s16x4 pb; \
    pb[0] = f2bf(p0); pb[1] = f2bf(p1); pb[2] = f2bf(p2); pb[3] = f2bf(p3); \
    o0 = mfma16(vf0##S, pb, o0); \
    o1 = mfma16(vf1##S, pb, o1); \
    o2 = mfma16(vf2##S, pb, o2); \
    o3 = mfma16(vf3##S, pb, o3); \
    m = mnew; \
  } while (0)

__global__ __launch_bounds__(512, 2) void attn(
    const short* __restrict__ q_hi, const short* __restrict__ q_lo,
    const short* __restrict__ k_hi, const short* __restrict__ k_lo,
    const short* __restrict__ v_t, float* __restrict__ out) {
  const int lane = threadIdx.x & 63;
  const int wv = threadIdx.x >> 6;   // 0..7
  const int col = lane & 15;
  const int g = lane >> 4;
  const int pr = blockIdx.x & 63;
  const int b = blockIdx.x >> 6;

  __shared__ float lds_O[8 * 64 * 18];   // 36 KiB
  __shared__ float lds_m[128];
  __shared__ float lds_l[128];

  const short* kh_b = k_hi + (size_t)b * 2048 * 64;
  const short* kl_b = k_lo + (size_t)b * 2048 * 64;
  const short* vt_b = v_t + (size_t)b * 64 * 2048;

#pragma unroll 1
  for (int half = 0; half < 2; ++half) {
    const int t = half ? (127 - pr) : pr;
    const int qb = t * 16;

    const short* qrh = q_hi + (size_t)(b * 2048 + qb + col) * 64 + g * 8;
    const short* qrl = q_lo + (size_t)(b * 2048 + qb + col) * 64 + g * 8;
    s16x8 qh0 = *(const s16x8*)(qrh);
    s16x8 qh1 = *(const s16x8*)(qrh + 32);
    s16x8 ql0 = *(const s16x8*)(qrl);
    s16x8 ql1 = *(const s16x8*)(qrl + 32);

    f32x4 o0 = {0,0,0,0}, o1 = {0,0,0,0}, o2 = {0,0,0,0}, o3 = {0,0,0,0};
    float m = -3.0e38f, l = 0.0f;

    KV_DECL(A); KV_DECL(B);
    int kt = wv;
    if (kt <= t) {
      KV_LOAD(A, kt);
      while (true) {
        {
          const int ktn = (kt + 8 <= t) ? kt + 8 : kt;
          KV_LOAD(B, ktn);
        }
        KV_COMPUTE(A, kt);
        kt += 8;
        if (kt > t) break;
        {
          const int ktn = (kt + 8 <= t) ? kt + 8 : kt;
          KV_LOAD(A, ktn);
        }
        KV_COMPUTE(B, kt);
        kt += 8;
        if (kt > t) break;
      }
    }

    // merge the 8 waves' partial (m, l, O^T) through LDS
    l += __shfl_xor(l, 16);
    l += __shfl_xor(l, 32);
    if (g == 0) {
      lds_m[wv * 16 + col] = m;
      lds_l[wv * 16 + col] = l;
    }
#pragma unroll
    for (int r = 0; r < 4; ++r) {
      lds_O[(wv * 64 +  0 + 4 * g + r) * 18 + col] = o0[r];
      lds_O[(wv * 64 + 16 + 4 * g + r) * 18 + col] = o1[r];
      lds_O[(wv * 64 + 32 + 4 * g + r) * 18 + col] = o2[r];
      lds_O[(wv * 64 + 48 + 4 * g + r) * 18 + col] = o3[r];
    }
    __syncthreads();
    {
      const int q = threadIdx.x & 15;
      const int hh = threadIdx.x >> 4;   // 0..31
      float mw[8], lw[8];
#pragma unroll
      for (int w = 0; w < 8; ++w) { mw[w] = lds_m[w * 16 + q]; lw[w] = lds_l[w * 16 + q]; }
      float M = mw[0];
#pragma unroll
      for (int w = 1; w < 8; ++w) M = fmaxf(M, mw[w]);
      float ew[8];
      float L = 0.0f;
#pragma unroll
      for (int w = 0; w < 8; ++w) { ew[w] = __builtin_amdgcn_exp2f((mw[w] - M) * LOG2E); L += ew[w] * lw[w]; }
      const float invL = 1.0f / L;
#pragma unroll
      for (int e = 0; e < 2; ++e) {
        const int h = hh * 2 + e;
        float acc = 0.0f;
#pragma unroll
        for (int w = 0; w < 8; ++w) acc += ew[w] * lds_O[(w * 64 + h) * 18 + q];
        out[(size_t)(b * 2048 + qb + q) * 64 + h] = acc * invL;
      }
    }
    __syncthreads();
  }
}

// ============================================================
extern "C" void kernel_launch(void* const* d_in, const int* in_sizes, int n_in,
                              void* d_out, int out_size, void* d_ws, size_t ws_size,
                              hipStream_t stream) {
  const float* x  = (const float*)d_in[0];
  const float* Wq = (const float*)d_in[1];
  const float* bq = (const float*)d_in[2];
  const float* Wk = (const float*)d_in[3];
  const float* bk = (const float*)d_in[4];
  const float* Wv = (const float*)d_in[5];
  const float* bv = (const float*)d_in[6];
  float* out = (float*)d_out;

  char* ws = (char*)d_ws;
  short* wt_hi = (short*)(ws);                       // 192*1024*2 = 393216 B
  short* wt_lo = (short*)(ws + 393216);
  short* q_hi  = (short*)(ws + 786432);              // 8192*64*2 = 1 MiB each
  short* q_lo  = (short*)(ws + 786432 + 1048576);
  short* k_hi  = (short*)(ws + 786432 + 2 * 1048576);
  short* k_lo  = (short*)(ws + 786432 + 3 * 1048576);
  short* v_t   = (short*)(ws + 786432 + 4 * 1048576);  // end: 6,029,312 B

  hipLaunchKernelGGL(prep_w, dim3(768), dim3(256), 0, stream, Wq, Wk, Wv, wt_hi, wt_lo);
  hipLaunchKernelGGL(proj_qkv, dim3(256), dim3(512), 0, stream,
                     x, wt_hi, wt_lo, bq, bk, bv, q_hi, q_lo, k_hi, k_lo, v_t);
  hipLaunchKernelGGL(attn, dim3(256), dim3(512), 0, stream,
                     q_hi, q_lo, k_hi, k_lo, v_t, out);
}

// Round 3
// 69.262 us; speedup vs baseline: 2.0808x; 1.4338x over previous
//
#include <hip/hip_runtime.h>

typedef float f32x4 __attribute__((ext_vector_type(4)));
typedef short s16x4 __attribute__((ext_vector_type(4)));
typedef short s16x8 __attribute__((ext_vector_type(8)));

#define LOG2E 1.4426950408889634f

// ---- bf16 helpers (bit-level, RNE) ----
__device__ __forceinline__ short f2bf(float f) {
  unsigned u = __float_as_uint(f);
  unsigned r = (u + 0x7fffu + ((u >> 16) & 1u)) >> 16;
  return (short)r;
}
__device__ __forceinline__ float bf2f(short s) {
  return __uint_as_float(((unsigned)(unsigned short)s) << 16);
}

// 16x16x16 bf16. D: col(lane&15)=B-idx, row(4g+reg)=A-idx  [HW-verified]
__device__ __forceinline__ f32x4 mfma16(s16x4 a, s16x4 b, f32x4 c) {
  return __builtin_amdgcn_mfma_f32_16x16x16bf16_1k(a, b, c, 0, 0, 0);
}
// 16x16x32 bf16 (gfx950). Same C/D layout. kappa-matched A/B (g,e)->g*8+e.
__device__ __forceinline__ f32x4 mfma32(s16x8 a, s16x8 b, f32x4 c) {
  return __builtin_amdgcn_mfma_f32_16x16x32_bf16(a, b, c, 0, 0, 0);
}

// async global->LDS, 16B per lane: HW writes lane i at (uniform base)+i*16.
__device__ __forceinline__ void gl_lds16(const void* gp, void* sp) {
  __builtin_amdgcn_global_load_lds(
      (__attribute__((address_space(1))) void*)const_cast<void*>(gp),
      (__attribute__((address_space(3))) void*)sp, 16, 0, 0);
}

// ============================================================
// Kernel 0: split W^T into bf16 hi/lo.  wt[n][c], n: 0-63 q, 64-127 k, 128-191 v
// ============================================================
__global__ __launch_bounds__(256) void prep_w(
    const float* __restrict__ Wq, const float* __restrict__ Wk, const float* __restrict__ Wv,
    short* __restrict__ wt_hi, short* __restrict__ wt_lo) {
  int idx = blockIdx.x * 256 + threadIdx.x;   // 192*1024 total
  int n = idx >> 10;
  int c = idx & 1023;
  const float* W = (n < 64) ? Wq : ((n < 128) ? Wk : Wv);
  float v = W[c * 64 + (n & 63)];
  short hi = f2bf(v);
  short lo = f2bf(v - bf2f(hi));
  wt_hi[idx] = hi;
  wt_lo[idx] = lo;
}

// ============================================================
// Kernel 1: QKV projection, m97-style 2-phase LDS pipeline.
// grid 256 x 512 thr. BM=32 tokens, BK=32, K-steps=32, dbuf LDS 48KB.
// W (hi 192 rows + lo 128 rows) staged via global_load_lds (async DMA).
// x reg-staged: f32x4 load issued early, split->ds_write late (T14).
// LDS k-group XOR swizzle: phys_g = g ^ ((row>>1)&3)  (2-way max = free).
// Wave (mg,ng): M-frag mg, N-frags {q:ng, k:4+ng, v:8+ng}. 7 mfma32/step.
// ============================================================
__global__ __launch_bounds__(512, 2) void proj_qkv(
    const float* __restrict__ x,
    const short* __restrict__ wt_hi, const short* __restrict__ wt_lo,
    const float* __restrict__ bq, const float* __restrict__ bk, const float* __restrict__ bv,
    short* __restrict__ q_hi, short* __restrict__ q_lo,
    short* __restrict__ k_hi, short* __restrict__ k_lo,
    short* __restrict__ v_t) {
  const int tid = threadIdx.x;
  const int lane = tid & 63;
  const int wv = tid >> 6;       // 0..7
  const int col = lane & 15;
  const int g = lane >> 4;       // 0..3
  const int mg = wv >> 2;        // 0..1
  const int ng = wv & 3;         // 0..3
  const int tokbase = blockIdx.x * 32;

  // per-buffer element offsets: whi[192][32] @0 ; wlo[128][32] @6144 ;
  // xhi[32][32] @10240 ; xlo[32][32] @11264.  buffer = 12288 shorts = 24KB.
  __shared__ short lds[2][12288];

  // ---- staging roles ----
  const int rl = lane >> 2, gp = lane & 3;       // W-chunk: row_local, phys slot
  const int xr = tid >> 3, xh_ = tid & 7;        // x-stage (tid<256): row, eighth
  const int xg = xh_ >> 1, xe = (xh_ & 1) * 4;
  const int xswz = ((xg ^ ((xr >> 1) & 3)) << 3) + xe;
  const float* xsrc = x + (size_t)(tokbase + xr) * 1024 + xh_ * 4;

  // ---- compute-side ds_read element offsets (step-invariant) ----
  const int atok = mg * 16 + col;
  const int xrd = atok * 32 + ((g ^ ((atok >> 1) & 3)) << 3);
  const int qrow = ng * 16 + col;
  const int krow = 64 + ng * 16 + col;
  const int vrow = 128 + ng * 16 + col;
  const int qrd = qrow * 32 + ((g ^ ((qrow >> 1) & 3)) << 3);
  const int krd = krow * 32 + ((g ^ ((krow >> 1) & 3)) << 3);
  const int vrd = vrow * 32 + ((g ^ ((vrow >> 1) & 3)) << 3);

  f32x4 accQ = {0,0,0,0}, accK = {0,0,0,0}, accV = {0,0,0,0};

  // stage W for step s into bufp: 20 chunks x 512 elems (16 rows x 32)
#define STAGE_W(bufp, s) do { \
    _Pragma("unroll") \
    for (int j = 0; j < 3; ++j) { \
      const int c = wv + 8 * j; \
      if (c < 20) { \
        const int wr = ((c < 12) ? (c * 16) : ((c - 12) * 16)) + rl; \
        const short* src = ((c < 12) ? wt_hi : wt_lo) + \
            (size_t)wr * 1024 + (s) * 32 + ((gp ^ ((wr >> 1) & 3)) << 3); \
        short* dst = (bufp) + ((c < 12) ? (c * 512) : (6144 + (c - 12) * 512)); \
        gl_lds16(src, dst); \
      } \
    } \
  } while (0)

#define STAGE_X_WRITE(bufp) do { \
    if (tid < 256) { \
      s16x4 hi4, lo4; \
      _Pragma("unroll") for (int i = 0; i < 4; ++i) { \
        short h = f2bf(xv[i]); hi4[i] = h; lo4[i] = f2bf(xv[i] - bf2f(h)); } \
      *(s16x4*)((bufp) + 10240 + xr * 32 + xswz) = hi4; \
      *(s16x4*)((bufp) + 11264 + xr * 32 + xswz) = lo4; \
    } \
  } while (0)

#define COMPUTE(bufp) do { \
    const short* bp = (bufp); \
    s16x8 xhf = *(const s16x8*)(bp + 10240 + xrd); \
    s16x8 xlf = *(const s16x8*)(bp + 11264 + xrd); \
    s16x8 qhf = *(const s16x8*)(bp + qrd); \
    s16x8 khf = *(const s16x8*)(bp + krd); \
    s16x8 vhf = *(const s16x8*)(bp + vrd); \
    s16x8 qlf = *(const s16x8*)(bp + 6144 + qrd); \
    s16x8 klf = *(const s16x8*)(bp + 6144 + krd); \
    accQ = mfma32(xhf, qhf, accQ); \
    accK = mfma32(xhf, khf, accK); \
    accV = mfma32(xhf, vhf, accV); \
    accQ = mfma32(xlf, qhf, accQ); \
    accK = mfma32(xlf, khf, accK); \
    accQ = mfma32(xhf, qlf, accQ); \
    accK = mfma32(xhf, klf, accK); \
  } while (0)

  // prologue: stage step 0 into buf0
  {
    f32x4 xv;
    if (tid < 256) xv = *(const f32x4*)(xsrc);
    STAGE_W(lds[0], 0);
    STAGE_X_WRITE(lds[0]);          // compiler inserts vmcnt for xv
    __syncthreads();                // drains global_load_lds (vmcnt 0) + ds
  }
#pragma unroll 1
  for (int s = 0; s < 32; ++s) {
    const int cur = s & 1;
    const int sn = s + 1;
    f32x4 xv;
    if (sn < 32) {
      if (tid < 256) xv = *(const f32x4*)(xsrc + sn * 32);
      STAGE_W(lds[cur ^ 1], sn);
    }
    COMPUTE(lds[cur]);
    if (sn < 32) STAGE_X_WRITE(lds[cur ^ 1]);
    __syncthreads();
  }

  // epilogue: bias, split, store. D: col(lane&15)=head idx, row(4g+r)=token.
  {
    const int hQ = ng * 16 + col;
    const float biasq = bq[hQ];
    const float biask = bk[hQ];
    const float biasv = bv[hQ];
#pragma unroll
    for (int r = 0; r < 4; ++r) {
      const int tok = tokbase + mg * 16 + 4 * g + r;
      float fq = accQ[r] + biasq;
      short qh = f2bf(fq);
      q_hi[(size_t)tok * 64 + hQ] = qh;
      q_lo[(size_t)tok * 64 + hQ] = f2bf(fq - bf2f(qh));
      float fk = accK[r] + biask;
      short kh = f2bf(fk);
      k_hi[(size_t)tok * 64 + hQ] = kh;
      k_lo[(size_t)tok * 64 + hQ] = f2bf(fk - bf2f(kh));
      const int bb = tok >> 11;
      const int tl = tok & 2047;
      v_t[((size_t)bb * 64 + hQ) * 2048 + tl] = f2bf(accV[r] + biasv);
    }
  }
#undef STAGE_W
#undef STAGE_X_WRITE
#undef COMPUTE
}

// ============================================================
// Kernel 2: causal flash attention, dual-tile. grid = 4b x 64 pairs, 512 thr.
// Tiles t (=pr) and tB (=127-pr) processed CONCURRENTLY sharing KV loads
// (t <= 63 < 64 <= tB always, so A-range subset of B-range). 2 indep chains.
// Waves split key-tiles mod 8; KV 2-deep register prefetch; 8-way LDS merge.
// ============================================================
#define KV_DECL(S) s16x8 kh0##S, kh1##S, kl0##S, kl1##S; s16x4 vf0##S, vf1##S, vf2##S, vf3##S
#define KV_LOAD(S, ktv) do { \
    const int _kb = (ktv) * 16; \
    const short* _krh = kh_b + (size_t)(_kb + col) * 64 + g * 8; \
    const short* _krl = kl_b + (size_t)(_kb + col) * 64 + g * 8; \
    kh0##S = *(const s16x8*)(_krh); \
    kh1##S = *(const s16x8*)(_krh + 32); \
    kl0##S = *(const s16x8*)(_krl); \
    kl1##S = *(const s16x8*)(_krl + 32); \
    const short* _vrow = vt_b + (size_t)col * 2048 + _kb + 4 * g; \
    vf0##S = *(const s16x4*)(_vrow); \
    vf1##S = *(const s16x4*)(_vrow + 16 * 2048); \
    vf2##S = *(const s16x4*)(_vrow + 32 * 2048); \
    vf3##S = *(const s16x4*)(_vrow + 48 * 2048); \
  } while (0)
// one online-softmax step of one q-tile against KV buffer S
#define TILE_STEP(S, ktv, tdiag, mm, ll, O0, O1, O2, O3, Qh0, Qh1, Ql0, Ql1) do { \
    f32x4 sA_ = {0,0,0,0}, sB_ = {0,0,0,0}, sC_ = {0,0,0,0}; \
    sA_ = mfma32(kh0##S, Qh0, sA_); sA_ = mfma32(kh1##S, Qh1, sA_); \
    sB_ = mfma32(kh0##S, Ql0, sB_); sB_ = mfma32(kh1##S, Ql1, sB_); \
    sC_ = mfma32(kl0##S, Qh0, sC_); sC_ = mfma32(kl1##S, Qh1, sC_); \
    float s0 = sA_[0] + sB_[0] + sC_[0]; \
    float s1 = sA_[1] + sB_[1] + sC_[1]; \
    float s2 = sA_[2] + sB_[2] + sC_[2]; \
    float s3 = sA_[3] + sB_[3] + sC_[3]; \
    if ((ktv) == (tdiag)) { \
      const int keyl = 4 * g; \
      if (keyl + 0 > col) s0 = -3.0e38f; \
      if (keyl + 1 > col) s1 = -3.0e38f; \
      if (keyl + 2 > col) s2 = -3.0e38f; \
      if (keyl + 3 > col) s3 = -3.0e38f; \
    } \
    float mx = fmaxf(fmaxf(s0, s1), fmaxf(s2, s3)); \
    mx = fmaxf(mx, __shfl_xor(mx, 16)); \
    mx = fmaxf(mx, __shfl_xor(mx, 32)); \
    const float mnew = fmaxf(mm, mx); \
    const float sc2 = __builtin_amdgcn_exp2f((mm - mnew) * LOG2E); \
    const float p0 = __builtin_amdgcn_exp2f((s0 - mnew) * LOG2E); \
    const float p1 = __builtin_amdgcn_exp2f((s1 - mnew) * LOG2E); \
    const float p2 = __builtin_amdgcn_exp2f((s2 - mnew) * LOG2E); \
    const float p3 = __builtin_amdgcn_exp2f((s3 - mnew) * LOG2E); \
    ll = ll * sc2 + (p0 + p1 + p2 + p3); \
    O0 *= sc2; O1 *= sc2; O2 *= sc2; O3 *= sc2; \
    s16x4 pb; \
    pb[0] = f2bf(p0); pb[1] = f2bf(p1); pb[2] = f2bf(p2); pb[3] = f2bf(p3); \
    O0 = mfma16(vf0##S, pb, O0); \
    O1 = mfma16(vf1##S, pb, O1); \
    O2 = mfma16(vf2##S, pb, O2); \
    O3 = mfma16(vf3##S, pb, O3); \
    mm = mnew; \
  } while (0)
#define KV_COMPUTE(S, ktv) do { \
    TILE_STEP(S, ktv, tB, mB, lB, oB0, oB1, oB2, oB3, qh0B, qh1B, ql0B, ql1B); \
    if ((ktv) <= t) \
      TILE_STEP(S, ktv, t, mA, lA, oA0, oA1, oA2, oA3, qh0A, qh1A, ql0A, ql1A); \
  } while (0)
// merge one tile's 8 wave-partials through LDS and store
#define MERGE(tt, mm, ll, O0, O1, O2, O3) do { \
    float lred = ll; \
    lred += __shfl_xor(lred, 16); \
    lred += __shfl_xor(lred, 32); \
    if (g == 0) { lds_m[wv * 16 + col] = mm; lds_l[wv * 16 + col] = lred; } \
    _Pragma("unroll") \
    for (int r = 0; r < 4; ++r) { \
      lds_O[(wv * 64 +  0 + 4 * g + r) * 18 + col] = O0[r]; \
      lds_O[(wv * 64 + 16 + 4 * g + r) * 18 + col] = O1[r]; \
      lds_O[(wv * 64 + 32 + 4 * g + r) * 18 + col] = O2[r]; \
      lds_O[(wv * 64 + 48 + 4 * g + r) * 18 + col] = O3[r]; \
    } \
    __syncthreads(); \
    { \
      const int q = tid & 15; \
      const int hh = tid >> 4; \
      float M = lds_m[q]; \
      _Pragma("unroll") \
      for (int w = 1; w < 8; ++w) M = fmaxf(M, lds_m[w * 16 + q]); \
      float ew[8]; \
      float L = 0.0f; \
      _Pragma("unroll") \
      for (int w = 0; w < 8; ++w) { \
        ew[w] = __builtin_amdgcn_exp2f((lds_m[w * 16 + q] - M) * LOG2E); \
        L += ew[w] * lds_l[w * 16 + q]; \
      } \
      const float invL = 1.0f / L; \
      _Pragma("unroll") \
      for (int e = 0; e < 2; ++e) { \
        const int h = hh * 2 + e; \
        float acc = 0.0f; \
        _Pragma("unroll") \
        for (int w = 0; w < 8; ++w) acc += ew[w] * lds_O[(w * 64 + h) * 18 + q]; \
        out[(size_t)(b * 2048 + (tt) * 16 + q) * 64 + h] = acc * invL; \
      } \
    } \
    __syncthreads(); \
  } while (0)

__global__ __launch_bounds__(512, 2) void attn(
    const short* __restrict__ q_hi, const short* __restrict__ q_lo,
    const short* __restrict__ k_hi, const short* __restrict__ k_lo,
    const short* __restrict__ v_t, float* __restrict__ out) {
  const int tid = threadIdx.x;
  const int lane = tid & 63;
  const int wv = tid >> 6;   // 0..7
  const int col = lane & 15;
  const int g = lane >> 4;
  const int pr = blockIdx.x & 63;
  const int b = blockIdx.x >> 6;
  const int t = pr;           // small tile (0..63)
  const int tB = 127 - pr;    // big tile (64..127)

  __shared__ float lds_O[8 * 64 * 18];   // 36 KiB
  __shared__ float lds_m[128];
  __shared__ float lds_l[128];

  const short* kh_b = k_hi + (size_t)b * 2048 * 64;
  const short* kl_b = k_lo + (size_t)b * 2048 * 64;
  const short* vt_b = v_t + (size_t)b * 64 * 2048;

  // Q fragments for both tiles
  const short* qrhA = q_hi + (size_t)(b * 2048 + t * 16 + col) * 64 + g * 8;
  const short* qrlA = q_lo + (size_t)(b * 2048 + t * 16 + col) * 64 + g * 8;
  const short* qrhB = q_hi + (size_t)(b * 2048 + tB * 16 + col) * 64 + g * 8;
  const short* qrlB = q_lo + (size_t)(b * 2048 + tB * 16 + col) * 64 + g * 8;
  s16x8 qh0A = *(const s16x8*)(qrhA);
  s16x8 qh1A = *(const s16x8*)(qrhA + 32);
  s16x8 ql0A = *(const s16x8*)(qrlA);
  s16x8 ql1A = *(const s16x8*)(qrlA + 32);
  s16x8 qh0B = *(const s16x8*)(qrhB);
  s16x8 qh1B = *(const s16x8*)(qrhB + 32);
  s16x8 ql0B = *(const s16x8*)(qrlB);
  s16x8 ql1B = *(const s16x8*)(qrlB + 32);

  f32x4 oA0 = {0,0,0,0}, oA1 = {0,0,0,0}, oA2 = {0,0,0,0}, oA3 = {0,0,0,0};
  f32x4 oB0 = {0,0,0,0}, oB1 = {0,0,0,0}, oB2 = {0,0,0,0}, oB3 = {0,0,0,0};
  float mA = -3.0e38f, lA = 0.0f;
  float mB = -3.0e38f, lB = 0.0f;

  KV_DECL(P); KV_DECL(Q);
  int kt = wv;                 // wv <= 7 < 64 <= tB: every wave has B-work
  KV_LOAD(P, kt);
  while (true) {
    { const int ktn = (kt + 8 <= tB) ? kt + 8 : kt; KV_LOAD(Q, ktn); }
    KV_COMPUTE(P, kt);
    kt += 8;
    if (kt > tB) break;
    { const int ktn = (kt + 8 <= tB) ? kt + 8 : kt; KV_LOAD(P, ktn); }
    KV_COMPUTE(Q, kt);
    kt += 8;
    if (kt > tB) break;
  }

  MERGE(t,  mA, lA, oA0, oA1, oA2, oA3);
  MERGE(tB, mB, lB, oB0, oB1, oB2, oB3);
}

// ============================================================
extern "C" void kernel_launch(void* const* d_in, const int* in_sizes, int n_in,
                              void* d_out, int out_size, void* d_ws, size_t ws_size,
                              hipStream_t stream) {
  const float* x  = (const float*)d_in[0];
  const float* Wq = (const float*)d_in[1];
  const float* bq = (const float*)d_in[2];
  const float* Wk = (const float*)d_in[3];
  const float* bk = (const float*)d_in[4];
  const float* Wv = (const float*)d_in[5];
  const float* bv = (const float*)d_in[6];
  float* out = (float*)d_out;

  char* ws = (char*)d_ws;
  short* wt_hi = (short*)(ws);                       // 192*1024*2 = 393216 B
  short* wt_lo = (short*)(ws + 393216);
  short* q_hi  = (short*)(ws + 786432);              // 8192*64*2 = 1 MiB each
  short* q_lo  = (short*)(ws + 786432 + 1048576);
  short* k_hi  = (short*)(ws + 786432 + 2 * 1048576);
  short* k_lo  = (short*)(ws + 786432 + 3 * 1048576);
  short* v_t   = (short*)(ws + 786432 + 4 * 1048576);  // end: 6,029,312 B

  hipLaunchKernelGGL(prep_w, dim3(768), dim3(256), 0, stream, Wq, Wk, Wv, wt_hi, wt_lo);
  hipLaunchKernelGGL(proj_qkv, dim3(256), dim3(512), 0, stream,
                     x, wt_hi, wt_lo, bq, bk, bv, q_hi, q_lo, k_hi, k_lo, v_t);
  hipLaunchKernelGGL(attn, dim3(256), dim3(512), 0, stream,
                     q_hi, q_lo, k_hi, k_lo, v_t, out);
}